// Round 3
// baseline (202.292 us; speedup 1.0000x reference)
//
#include <hip/hip_runtime.h>
#include <hip/hip_bf16.h>

#define IMG_W 224
#define NPIX (IMG_W * IMG_W)
#define FOCAL 500.0f

// === Round-2 prediction ledger (diff first real bench against this) ===
// project_kernel: FETCH ~48 MB (point stream, nontemporal), dur 8-45 us
//                 ~2.2M u64 atomicMin into 400KB zbuf (L2-resident)
// resolve_kernel: ~0.6 MB gather + 1.8 MB store, dur ~1-3 us
// total dur_us <= ~12  -> streaming roofline, stop.
// total dur_us 20-60   -> atomic-rate-bound, try LDS pre-reduction next.

typedef float f4 __attribute__((ext_vector_type(4)));

// Pass 1: project points, z-buffer via packed u64 atomicMin.
// packed = (depth_bits << 32) | point_index. depth > 0.1 > 0 so float bits
// order identically to unsigned. Sentinel ~0ULL = "no winner".
__global__ void __launch_bounds__(256) project_kernel(
    const float* __restrict__ pc,       // (N,3)
    const float* __restrict__ cam_pos,  // (3,)
    const float* __restrict__ cam_rot,  // (3,3) row-major
    unsigned long long* __restrict__ zbuf,
    int n)                              // number of points
{
    // camera params are wave-uniform -> scalar loads
    const float cx = cam_pos[0], cy = cam_pos[1], cz = cam_pos[2];
    const float r00 = cam_rot[0], r01 = cam_rot[1], r02 = cam_rot[2];
    const float r10 = cam_rot[3], r11 = cam_rot[4], r12 = cam_rot[5];
    const float r20 = cam_rot[6], r21 = cam_rot[7], r22 = cam_rot[8];

    const int tid = blockIdx.x * blockDim.x + threadIdx.x;
    const int base = tid * 4;              // 4 points per thread
    if (base >= n) return;

    float px[4], py[4], pz[4];
    int cnt;
    if (base + 4 <= n) {
        // 48 B = 3 x float4 (16B aligned: tid*48 bytes). Non-temporal: the
        // point stream is read once; keep it from evicting the hot zbuf in L2.
        const f4* pc4 = reinterpret_cast<const f4*>(pc) + (size_t)tid * 3;
        f4 a = __builtin_nontemporal_load(pc4 + 0);
        f4 b = __builtin_nontemporal_load(pc4 + 1);
        f4 c = __builtin_nontemporal_load(pc4 + 2);
        px[0] = a.x; py[0] = a.y; pz[0] = a.z;
        px[1] = a.w; py[1] = b.x; pz[1] = b.y;
        px[2] = b.z; py[2] = b.w; pz[2] = c.x;
        px[3] = c.y; py[3] = c.z; pz[3] = c.w;
        cnt = 4;
    } else {
        cnt = n - base;
        for (int k = 0; k < cnt; ++k) {
            px[k] = pc[(size_t)(base + k) * 3 + 0];
            py[k] = pc[(size_t)(base + k) * 3 + 1];
            pz[k] = pc[(size_t)(base + k) * 3 + 2];
        }
    }

    #pragma unroll
    for (int k = 0; k < 4; ++k) {
        if (k >= cnt) break;
        const float dx = px[k] - cx, dy = py[k] - cy, dz = pz[k] - cz;
        const float zc = r20 * dx + r21 * dy + r22 * dz;
        if (!(zc > 0.1f)) continue;                       // valid = z > 0.1
        const float xc = r00 * dx + r01 * dy + r02 * dz;
        const float yc = r10 * dx + r11 * dy + r12 * dz;
        const float inv = FOCAL / zc;
        const float x = xc * inv + (float)(IMG_W / 2);
        const float y = yc * inv + (float)(IMG_W / 2);
        if (!(x >= 0.0f && x < (float)IMG_W && y >= 0.0f && y < (float)IMG_W))
            continue;                                     // in_bounds (float compare)
        const int xi = (int)x;                            // trunc == floor, x >= 0
        const int yi = (int)y;
        const int pid = yi * IMG_W + xi;
        const unsigned long long pk =
            ((unsigned long long)__float_as_uint(zc) << 32) |
            (unsigned int)(base + k);
        atomicMin(&zbuf[pid], pk);
    }
}

// Pass 2: per pixel, gather winner color, write CHW float32 image.
__global__ void __launch_bounds__(256) resolve_kernel(
    const unsigned long long* __restrict__ zbuf,
    const float* __restrict__ colors,   // (N,3)
    float* __restrict__ out)            // (3, 224, 224) flattened
{
    const int p = blockIdx.x * blockDim.x + threadIdx.x;
    if (p >= NPIX) return;
    const unsigned long long pk = zbuf[p];
    float r = 0.0f, g = 0.0f, b = 0.0f;
    if (pk != ~0ULL) {
        const unsigned idx = (unsigned)(pk & 0xFFFFFFFFu);
        r = colors[(size_t)idx * 3 + 0];
        g = colors[(size_t)idx * 3 + 1];
        b = colors[(size_t)idx * 3 + 2];
    }
    out[0 * NPIX + p] = r;
    out[1 * NPIX + p] = g;
    out[2 * NPIX + p] = b;
}

extern "C" void kernel_launch(void* const* d_in, const int* in_sizes, int n_in,
                              void* d_out, int out_size, void* d_ws, size_t ws_size,
                              hipStream_t stream)
{
    const float* pc      = (const float*)d_in[0];  // point_cloud (N,3)
    const float* cam_pos = (const float*)d_in[1];  // (3,)
    const float* cam_rot = (const float*)d_in[2];  // (3,3)
    const float* colors  = (const float*)d_in[3];  // (N,3)
    float* out = (float*)d_out;

    const int n = in_sizes[0] / 3;  // number of points

    unsigned long long* zbuf = (unsigned long long*)d_ws;  // NPIX * 8 bytes

    // init z-buffer to ~0ULL (graph-capture-safe async memset)
    hipMemsetAsync(zbuf, 0xFF, (size_t)NPIX * sizeof(unsigned long long), stream);

    const int threads = 256;
    const int nThreads = (n + 3) / 4;                     // 4 points/thread
    const int blocks = (nThreads + threads - 1) / threads;
    project_kernel<<<blocks, threads, 0, stream>>>(pc, cam_pos, cam_rot, zbuf, n);

    const int pblocks = (NPIX + threads - 1) / threads;
    resolve_kernel<<<pblocks, threads, 0, stream>>>(zbuf, colors, out);
}